// Round 1
// baseline (1113.958 us; speedup 1.0000x reference)
//
#include <hip/hip_runtime.h>

typedef unsigned int u32;
typedef unsigned long long u64;

// ---------------- problem constants ----------------
#define NCLS 80
#define NIMG 8
#define PRE_K 1000
#define POST_K 100
// level sizes
// HW: 15200, 3800, 950 ; W: 152,76,38 ; strides 8,16,32
// concat loc bases: 0, 15200, 19000 ; total 19950

__device__ __forceinline__ int HWof(int l){ return l==0?15200:(l==1?3800:950); }
__device__ __forceinline__ int BASEof(int l){ return l==0?0:(l==1?15200:19000); }
__device__ __forceinline__ float STRof(int l){ return l==0?8.f:(l==1?16.f:32.f); }

struct Ptrs {
  const float* logits[3];
  const float* reg[3];
  const float* ctr[3];
  const float* cofs[3];
  const float* locs[3];
};

// ---------------- workspace layout (bytes) ----------------
// zeroed every launch:
#define OFF_HIST1 0u            // 24*4096*4 = 393216
#define OFF_HIST2 393216u       // 393216
#define OFF_CAND  786432u       // 24*4
#define OFF_PCNT  786528u       // 24*4
#define OFF_THR   786624u       // 24*4*4 = 384  (fields: B1, cntAbove1, T24, n_l)
#define OFF_MCNT  787008u       // 8*4
#define ZERO_BYTES 787040u
// not zeroed:
#define OFF_SCTR  787072u       // 8*19950*4 = 638400
#define OFF_POOL  1425472u      // 24*2048*8 = 393216
#define OFF_SORT  1818688u      // 24*1024*8 = 196608
#define OFF_MERG  2015296u      // 8*3072*8*4 = 786432
// total need ~2801728 bytes

__device__ __forceinline__ float sigmoidf(float x){ return 1.0f/(1.0f+expf(-x)); }

// ---------------- K0: sigmoid(ctr) for all (img, concat-loc) ----------------
__global__ void sctr_kernel(Ptrs p, float* sctr){
  int img = blockIdx.y;
  int i = blockIdx.x*256 + threadIdx.x;
  if (i >= 19950) return;
  int l, loc;
  if (i < 15200){ l=0; loc=i; }
  else if (i < 19000){ l=1; loc=i-15200; }
  else { l=2; loc=i-19000; }
  int HW = HWof(l);
  float x = p.ctr[l][(size_t)img*HW + loc];
  sctr[img*19950 + i] = sigmoidf(x);
}

// ---------------- K1/K3/K5: data passes ----------------
// PASS 1: coarse 4096-bin histogram of score fp32 bits>>20 + candidate count
// PASS 2: refine histogram ((bits>>8)&0xFFF) for elements whose coarse bin == B1
// PASS 3: compact all elements with (bits>>8) >= T24 into pool (64-bit keys)
template<int PASS>
__global__ void pass_kernel(Ptrs p, const float* sctr, u32* hist1, u32* hist2,
                            u32* cand, u32* pcnt, u32* thr, u64* pool){
  const int lvl = blockIdx.z, img = blockIdx.y, grp = blockIdx.x;
  const int HW = HWof(lvl), base = BASEof(lvl);
  const int pair = img*3 + lvl;
  __shared__ u32 lh[4096];
  __shared__ u32 lcand;
  u32 B1 = 0, T24 = 0;
  if (PASS==1 || PASS==2){
    for (int b=threadIdx.x; b<4096; b+=256) lh[b]=0;
  }
  if (PASS==1 && threadIdx.x==0) lcand = 0;
  if (PASS==2) B1  = thr[pair*4+0];
  if (PASS==3) T24 = thr[pair*4+2];
  __syncthreads();
  u32 my_cand = 0;
  const float* sc_ptr = sctr + img*19950 + base;
  for (int cg=0; cg<8; ++cg){
    int cls = grp*8 + cg;
    const float* lg = p.logits[lvl] + (size_t)(img*NCLS + cls)*HW;
    for (int loc=threadIdx.x; loc<HW; loc+=256){
      float sl = sigmoidf(lg[loc]);
      if (sl > 0.05f){
        float sc = sl * sc_ptr[loc];
        u32 bits = __float_as_uint(sc);
        if (PASS==1){ my_cand++; atomicAdd(&lh[bits>>20], 1u); }
        if (PASS==2){ if ((bits>>20)==B1) atomicAdd(&lh[(bits>>8)&0xFFFu], 1u); }
        if (PASS==3){
          if ((bits>>8) >= T24){
            u32 idx = atomicAdd(&pcnt[pair], 1u);
            if (idx < 2048u)
              pool[(size_t)pair*2048 + idx] =
                ((u64)bits<<32) | (u64)(0xFFFFFFFFu - (u32)(loc*NCLS + cls));
          }
        }
      }
    }
  }
  if (PASS==1){
    atomicAdd(&lcand, my_cand);
    __syncthreads();
    if (threadIdx.x==0 && lcand) atomicAdd(&cand[pair], lcand);
    for (int b=threadIdx.x; b<4096; b+=256)
      if (lh[b]) atomicAdd(&hist1[pair*4096+b], lh[b]);
  }
  if (PASS==2){
    __syncthreads();
    for (int b=threadIdx.x; b<4096; b+=256)
      if (lh[b]) atomicAdd(&hist2[pair*4096+b], lh[b]);
  }
}

// ---------------- K2/K4: descending scan to find boundary bin ----------------
template<bool FINE>
__global__ void scan_kernel(const u32* hist, const u32* cand, u32* thr){
  const int pair = blockIdx.x;
  const u32* h = hist + pair*4096;
  __shared__ u32 seg[256];
  __shared__ u32 excl[256];
  __shared__ u32 sKK;
  if (threadIdx.x==0){
    u32 kk = cand[pair]; if (kk > (u32)PRE_K) kk = PRE_K;
    if (FINE){
      if (kk) kk -= thr[pair*4+1];
    } else {
      thr[pair*4+3] = kk;               // n_l (provisional)
      if (kk==0){ thr[pair*4+0]=0xFFFFu; thr[pair*4+2]=0xFFFFFFFFu; }
    }
    sKK = kk;
  }
  __syncthreads();
  u32 KK = sKK;
  if (KK==0) return;
  int t = threadIdx.x;
  u32 part = 0;
  for (int k=0;k<16;++k) part += h[4095 - (t*16+k)];
  seg[t] = part;
  __syncthreads();
  if (t==0){ u32 run=0; for (int i=0;i<256;++i){ excl[i]=run; run+=seg[i]; } }
  __syncthreads();
  u32 cum = excl[t];
  for (int k=0;k<16;++k){
    int bin = 4095 - (t*16+k);
    u32 c = h[bin];
    if (c && cum < KK && cum + c >= KK){
      if (!FINE){ thr[pair*4+0]=(u32)bin; thr[pair*4+1]=cum; }
      else {
        u32 B1 = thr[pair*4+0];
        thr[pair*4+2] = (B1<<12) | (u32)bin;   // T24 threshold on bits>>8
      }
    }
    cum += c;
  }
}

// ---------------- K6: per-pair bitonic sort of pool, emit top n_l keys -------
__global__ void sort_kernel(const u32* pcnt, u32* thr, const u64* pool, u64* sorted){
  const int pair = blockIdx.x;
  __shared__ u64 a[2048];
  int n = (int)min(pcnt[pair], 2048u);
  for (int i=threadIdx.x; i<2048; i+=256)
    a[i] = (i<n) ? pool[(size_t)pair*2048+i] : 0ull;
  __syncthreads();
  for (int k=2; k<=2048; k<<=1){
    for (int j=k>>1; j>0; j>>=1){
      for (int i=threadIdx.x; i<2048; i+=256){
        int ix = i ^ j;
        if (ix > i){
          u64 x=a[i], y=a[ix];
          bool up = ((i & k)==0);        // descending overall
          if (up ? (x<y) : (x>y)){ a[i]=y; a[ix]=x; }
        }
      }
      __syncthreads();
    }
  }
  int KK = (int)thr[pair*4+3];
  int m = KK < n ? KK : n;
  for (int r=threadIdx.x; r<m; r+=256) sorted[(size_t)pair*1024+r] = a[r];
  if (threadIdx.x==0) thr[pair*4+3] = (u32)m;
}

// ---------------- K7: 3-way stable merge + box decode ----------------
__global__ void merge_kernel(Ptrs p, const u32* thr, const u64* sorted,
                             float* merged, u32* mcnt){
#pragma clang fp contract(off)
  const int img = blockIdx.x;
  __shared__ u64 mk[3][1024];
  __shared__ int n[3];
  if (threadIdx.x < 3) n[threadIdx.x] = (int)thr[(img*3+threadIdx.x)*4+3];
  __syncthreads();
  const int n0=n[0], n1=n[1], n2=n[2];
  for (int idx=threadIdx.x; idx<3*1024; idx+=blockDim.x){
    int l = idx>>10, r = idx&1023;
    if (r < n[l]){
      u64 key = sorted[(size_t)(img*3+l)*1024 + r];
      mk[l][r] = (key & 0xFFFFFFFF00000000ull) |
                 (u64)(0xFFFFFFFFu - (u32)(l*PRE_K + r));  // concat-idx tie-break
    }
  }
  __syncthreads();
  const int T = n0+n1+n2;
  if (threadIdx.x==0) mcnt[img] = (u32)T;
  for (int t=threadIdx.x; t<T; t+=blockDim.x){
    int l, r;
    if (t < n0){ l=0; r=t; }
    else if (t < n0+n1){ l=1; r=t-n0; }
    else { l=2; r=t-n0-n1; }
    u64 x = mk[l][r];
    int pos = r;
    #pragma unroll
    for (int o=0;o<3;++o) if (o!=l){
      int lo=0, hi=n[o];
      while (lo<hi){ int m=(lo+hi)>>1; if (mk[o][m] > x) lo=m+1; else hi=m; }
      pos += lo;
    }
    u64 key = sorted[(size_t)(img*3+l)*1024 + r];
    u32 flat = 0xFFFFFFFFu - (u32)(key & 0xFFFFFFFFull);
    float score = __uint_as_float((u32)(key>>32));
    int HW = HWof(l);
    int loc = (int)(flat / (u32)NCLS);
    int cls = (int)(flat - (u32)loc*NCLS);
    float lx = p.locs[l][2*loc], ly = p.locs[l][2*loc+1];
    float st = STRof(l);
    const float* rg = p.reg[l] + (size_t)img*4*HW + loc;
    float r0 = rg[0]*st, r1 = rg[HW]*st, r2 = rg[2*(size_t)HW]*st, r3 = rg[3*(size_t)HW]*st;
    float x1 = fminf(fmaxf(lx - r0, 0.f), 1216.f);
    float y1 = fminf(fmaxf(ly - r1, 0.f),  800.f);
    float x2 = fminf(fmaxf(lx + r2, 0.f), 1216.f);
    float y2 = fminf(fmaxf(ly + r3, 0.f),  800.f);
    float* out = merged + (size_t)(img*3072 + pos)*8;
    out[0]=x1; out[1]=y1; out[2]=x2; out[3]=y2;
    out[4]=score; out[5]=(float)cls; out[6]=(float)l; out[7]=(float)loc;
  }
}

// ---------------- K8: greedy NMS (class-offset boxes) + output ----------------
__global__ __launch_bounds__(1024)
void nms_kernel(Ptrs p, const float* merged_all, const u32* mcnt, float* out){
#pragma clang fp contract(off)
  const int img = blockIdx.x;
  const float* merged = merged_all + (size_t)img*3072*8;
  __shared__ float4 ob[3072];
  __shared__ unsigned char keep[3072];
  __shared__ unsigned short klist[128];
  const int T = (int)mcnt[img];
  for (int j=threadIdx.x; j<3072; j+=1024){
    if (j < T){
      const float* rec = merged + (size_t)j*8;
      float off = rec[5]*1217.0f;               // replicate ref's rounded offset boxes
      ob[j] = make_float4(rec[0]+off, rec[1]+off, rec[2]+off, rec[3]+off);
      keep[j] = 1;
    } else keep[j] = 0;
  }
  __syncthreads();
  int kept = 0;
  for (int i=0; i<T; ++i){
    if (!keep[i]) continue;
    if (threadIdx.x==0) klist[kept] = (unsigned short)i;
    kept++;
    if (kept >= POST_K) break;     // later boxes can only be suppressed -> irrelevant
    float4 bi = ob[i];
    float ai = (bi.z-bi.x)*(bi.w-bi.y);
    for (int j=i+1+(int)threadIdx.x; j<T; j+=1024){
      if (!keep[j]) continue;
      float4 bj = ob[j];
      float aj = (bj.z-bj.x)*(bj.w-bj.y);
      float ltx = fmaxf(bi.x,bj.x), lty = fmaxf(bi.y,bj.y);
      float rbx = fminf(bi.z,bj.z), rby = fminf(bi.w,bj.w);
      float wx = fmaxf(rbx-ltx, 0.f), wy = fmaxf(rby-lty, 0.f);
      float inter = wx*wy;
      float denom = ai + aj;
      denom = denom - inter;
      denom = denom + 1e-9f;
      if (inter/denom > 0.6f) keep[j] = 0;
    }
    __syncthreads();
  }
  __syncthreads();
  // ---- emit outputs: boxes[8][100][4] | scores[8][100] | cls[8][100] | cofs[8][100][128] | kv[8][100]
  float* obx = out;
  float* osc = out + 3200;
  float* ocl = out + 4000;
  float* ocf = out + 4800;
  float* okv = out + 107200;
  for (int r=threadIdx.x; r<POST_K; r+=1024){
    if (r < kept){
      int i = klist[r];
      const float* rec = merged + (size_t)i*8;
      obx[(img*POST_K+r)*4+0]=rec[0];
      obx[(img*POST_K+r)*4+1]=rec[1];
      obx[(img*POST_K+r)*4+2]=rec[2];
      obx[(img*POST_K+r)*4+3]=rec[3];
      osc[img*POST_K+r] = sqrtf(fmaxf(rec[4], 1e-12f));
      ocl[img*POST_K+r] = rec[5];
      okv[img*POST_K+r] = 1.0f;
    } else {
      obx[(img*POST_K+r)*4+0]=0.f;
      obx[(img*POST_K+r)*4+1]=0.f;
      obx[(img*POST_K+r)*4+2]=0.f;
      obx[(img*POST_K+r)*4+3]=0.f;
      osc[img*POST_K+r] = 0.f;
      ocl[img*POST_K+r] = -1.0f;
      okv[img*POST_K+r] = 0.f;
    }
  }
  for (int q=threadIdx.x; q<POST_K*128; q+=1024){
    int r = q>>7, d = q&127;
    float v = 0.f;
    if (r < kept){
      int i = klist[r];
      const float* rec = merged + (size_t)i*8;
      int l = (int)rec[6]; int loc = (int)rec[7];
      int HW = HWof(l);
      v = p.cofs[l][((size_t)img*128 + d)*HW + loc];
    }
    ocf[(img*POST_K+r)*128 + d] = v;
  }
}

// ---------------- host ----------------
extern "C" void kernel_launch(void* const* d_in, const int* in_sizes, int n_in,
                              void* d_out, int out_size, void* d_ws, size_t ws_size,
                              hipStream_t stream){
  Ptrs p;
  for (int l=0; l<3; ++l){
    p.locs[l]   = (const float*)d_in[5*l+0];
    p.logits[l] = (const float*)d_in[5*l+1];
    p.reg[l]    = (const float*)d_in[5*l+2];
    p.ctr[l]    = (const float*)d_in[5*l+3];
    p.cofs[l]   = (const float*)d_in[5*l+4];
  }
  char* ws = (char*)d_ws;
  u32* hist1  = (u32*)(ws + OFF_HIST1);
  u32* hist2  = (u32*)(ws + OFF_HIST2);
  u32* cand   = (u32*)(ws + OFF_CAND);
  u32* pcnt   = (u32*)(ws + OFF_PCNT);
  u32* thr    = (u32*)(ws + OFF_THR);
  u32* mcnt   = (u32*)(ws + OFF_MCNT);
  float* sctr = (float*)(ws + OFF_SCTR);
  u64* pool   = (u64*)(ws + OFF_POOL);
  u64* sorted = (u64*)(ws + OFF_SORT);
  float* merged = (float*)(ws + OFF_MERG);

  hipMemsetAsync(ws, 0, ZERO_BYTES, stream);
  sctr_kernel<<<dim3(78,8), 256, 0, stream>>>(p, sctr);
  pass_kernel<1><<<dim3(10,8,3), 256, 0, stream>>>(p, sctr, hist1, hist2, cand, pcnt, thr, pool);
  scan_kernel<false><<<24, 256, 0, stream>>>(hist1, cand, thr);
  pass_kernel<2><<<dim3(10,8,3), 256, 0, stream>>>(p, sctr, hist1, hist2, cand, pcnt, thr, pool);
  scan_kernel<true><<<24, 256, 0, stream>>>(hist2, cand, thr);
  pass_kernel<3><<<dim3(10,8,3), 256, 0, stream>>>(p, sctr, hist1, hist2, cand, pcnt, thr, pool);
  sort_kernel<<<24, 256, 0, stream>>>(pcnt, thr, pool, sorted);
  merge_kernel<<<8, 1024, 0, stream>>>(p, thr, sorted, merged, mcnt);
  nms_kernel<<<8, 1024, 0, stream>>>(p, merged, mcnt, (float*)d_out);
}

// Round 2
// 409.044 us; speedup vs baseline: 2.7233x; 2.7233x over previous
//
#include <hip/hip_runtime.h>

typedef unsigned int u32;
typedef unsigned long long u64;

// ---------------- problem constants ----------------
#define NCLS 80
#define NIMG 8
#define PRE_K 1000
#define POST_K 100
// HW: 15200, 3800, 950 ; strides 8,16,32 ; concat bases 0,15200,19000 ; total 19950

__device__ __forceinline__ int HWof(int l){ return l==0?15200:(l==1?3800:950); }
__device__ __forceinline__ int BASEof(int l){ return l==0?0:(l==1?15200:19000); }
__device__ __forceinline__ float STRof(int l){ return l==0?8.f:(l==1?16.f:32.f); }

struct Ptrs {
  const float* logits[3];
  const float* reg[3];
  const float* ctr[3];
  const float* cofs[3];
  const float* locs[3];
};

// ---------------- workspace layout (bytes) ----------------
// zeroed every launch:
#define OFF_HIST1 0u            // 24*4096*4 = 393216
#define OFF_HIST2 393216u       // 393216
#define OFF_CAND  786432u       // 24*4 -> 96
#define OFF_ACNT  786528u       // 96
#define OFF_BCNT  786624u       // 96
#define OFF_THR   786720u       // 24*4*4 = 384  (fields: B1, cntAbove1, T24, n_l)
#define OFF_MCNT  787104u       // 8*4
#define ZERO_BYTES 787136u
// not zeroed:
#define OFF_SCTR  787136u       // 8*19950*4 = 638400
#define OFF_APOOL 1425536u      // 24*1024*8 = 196608
#define OFF_BPOOL 1622144u      // 24*4096*8 = 786432
#define OFF_SORT  2408576u      // 24*1024*8 = 196608
#define OFF_MERG  2605184u      // 8*3072*8*4 = 786432
// total ~3391616 bytes

__device__ __forceinline__ float sigmoidf(float x){ return 1.0f/(1.0f+expf(-x)); }

// ---------------- K0: sigmoid(ctr) for all (img, concat-loc) ----------------
__global__ void sctr_kernel(Ptrs p, float* sctr){
  int img = blockIdx.y;
  int i = blockIdx.x*256 + threadIdx.x;
  if (i >= 19950) return;
  int l, loc;
  if (i < 15200){ l=0; loc=i; }
  else if (i < 19000){ l=1; loc=i-15200; }
  else { l=2; loc=i-19000; }
  int HW = HWof(l);
  float x = p.ctr[l][(size_t)img*HW + loc];
  sctr[img*19950 + i] = sigmoidf(x);
}

// ---------------- K1: coarse 4096-bin histogram (bits>>20) + cand count -----
// grid: (60*4, 8, 3); block owns 256 locs x 20 classes
__global__ void hist_kernel(Ptrs p, const float* sctr, u32* hist1, u32* cand){
  const int lvl = blockIdx.z, img = blockIdx.y;
  const int HW = HWof(lvl), base = BASEof(lvl);
  const int nchunk = (HW + 255) >> 8;
  const int chunk = blockIdx.x >> 2;
  const int cgrp  = blockIdx.x & 3;
  if (chunk >= nchunk) return;
  const int pair = img*3 + lvl;
  __shared__ u32 lh[4096];
  __shared__ u32 lcand;
  for (int b=threadIdx.x; b<4096; b+=256) lh[b]=0;
  if (threadIdx.x==0) lcand = 0;
  __syncthreads();
  const int loc = chunk*256 + (int)threadIdx.x;
  u32 my_cand = 0;
  if (loc < HW){
    const float sc_ctr = sctr[img*19950 + base + loc];
    const float* lg = p.logits[lvl] + (size_t)(img*NCLS + cgrp*20)*HW + loc;
    #pragma unroll 4
    for (int c=0; c<20; ++c){
      float sl = sigmoidf(lg[(size_t)c*HW]);
      if (sl > 0.05f){
        my_cand++;
        u32 bits = __float_as_uint(sl * sc_ctr);
        atomicAdd(&lh[bits>>20], 1u);
      }
    }
  }
  if (my_cand) atomicAdd(&lcand, my_cand);
  __syncthreads();
  if (threadIdx.x==0 && lcand) atomicAdd(&cand[pair], lcand);
  for (int b=threadIdx.x; b<4096; b+=256){
    u32 v = lh[b];
    if (v) atomicAdd(&hist1[pair*4096+b], v);
  }
}

// ---------------- K2/K4: descending scan to find boundary bin ----------------
template<bool FINE>
__global__ void scan_kernel(const u32* hist, const u32* cand, u32* thr){
  const int pair = blockIdx.x;
  const u32* h = hist + pair*4096;
  __shared__ u32 seg[256];
  __shared__ u32 excl[256];
  __shared__ u32 sKK;
  if (threadIdx.x==0){
    u32 kk = cand[pair]; if (kk > (u32)PRE_K) kk = PRE_K;
    if (FINE){
      if (kk) kk -= thr[pair*4+1];
    } else {
      thr[pair*4+3] = kk;               // n_l (provisional)
      if (kk==0){ thr[pair*4+0]=0xFFFFu; thr[pair*4+2]=0xFFFFFFFFu; }
    }
    sKK = kk;
  }
  __syncthreads();
  u32 KK = sKK;
  if (KK==0) return;
  int t = threadIdx.x;
  u32 part = 0;
  for (int k=0;k<16;++k) part += h[4095 - (t*16+k)];
  seg[t] = part;
  __syncthreads();
  if (t==0){ u32 run=0; for (int i=0;i<256;++i){ excl[i]=run; run+=seg[i]; } }
  __syncthreads();
  u32 cum = excl[t];
  for (int k=0;k<16;++k){
    int bin = 4095 - (t*16+k);
    u32 c = h[bin];
    if (c && cum < KK && cum + c >= KK){
      if (!FINE){ thr[pair*4+0]=(u32)bin; thr[pair*4+1]=cum; }
      else {
        u32 B1 = thr[pair*4+0];
        thr[pair*4+2] = (B1<<12) | (u32)bin;   // T24 threshold on bits>>8
      }
    }
    cum += c;
  }
}

// ---------------- K3: fused compact + refine (single extra data pass) --------
// elements with coarse bin > B1 -> apool (guaranteed < 1000 per pair)
// elements with coarse bin == B1 -> bpool + direct global fine-hist atomic
__global__ void compact_kernel(Ptrs p, const float* sctr, const u32* thr,
                               u32* hist2, u32* acnt, u32* bcnt,
                               u64* apool, u64* bpool){
  const int lvl = blockIdx.z, img = blockIdx.y;
  const int HW = HWof(lvl), base = BASEof(lvl);
  const int nchunk = (HW + 255) >> 8;
  const int chunk = blockIdx.x >> 2;
  const int cgrp  = blockIdx.x & 3;
  if (chunk >= nchunk) return;
  const int pair = img*3 + lvl;
  const u32 B1 = thr[pair*4+0];
  const int loc = chunk*256 + (int)threadIdx.x;
  if (loc >= HW) return;
  const float sc_ctr = sctr[img*19950 + base + loc];
  const float* lg = p.logits[lvl] + (size_t)(img*NCLS + cgrp*20)*HW + loc;
  #pragma unroll 4
  for (int c=0; c<20; ++c){
    float sl = sigmoidf(lg[(size_t)c*HW]);
    if (sl > 0.05f){
      u32 bits = __float_as_uint(sl * sc_ctr);
      u32 b1 = bits>>20;
      if (b1 > B1){
        u32 i = atomicAdd(&acnt[pair], 1u);
        if (i < 1024u)
          apool[(size_t)pair*1024 + i] =
            ((u64)bits<<32) | (u64)(0xFFFFFFFFu - (u32)(loc*NCLS + cgrp*20 + c));
      } else if (b1 == B1){
        atomicAdd(&hist2[pair*4096 + ((bits>>8)&0xFFFu)], 1u);
        u32 i = atomicAdd(&bcnt[pair], 1u);
        if (i < 4096u)
          bpool[(size_t)pair*4096 + i] =
            ((u64)bits<<32) | (u64)(0xFFFFFFFFu - (u32)(loc*NCLS + cgrp*20 + c));
      }
    }
  }
}

// ---------------- K5: gather apool + filtered bpool, bitonic sort, top n_l ---
__global__ __launch_bounds__(1024)
void sort_kernel(const u32* acnt, const u32* bcnt, u32* thr,
                 const u64* apool, const u64* bpool, u64* sorted){
  const int pair = blockIdx.x;
  __shared__ u64 a[2048];
  __shared__ u32 cnt;
  const int na = (int)min(acnt[pair], 1024u);
  for (int i=threadIdx.x; i<2048; i+=1024) a[i] = 0ull;
  if (threadIdx.x==0) cnt = (u32)na;
  __syncthreads();
  for (int i=threadIdx.x; i<na; i+=1024) a[i] = apool[(size_t)pair*1024 + i];
  const u32 T24 = thr[pair*4+2];
  const int nb = (int)min(bcnt[pair], 4096u);
  for (int i=threadIdx.x; i<nb; i+=1024){
    u64 k = bpool[(size_t)pair*4096 + i];
    if ((u32)(k>>40) >= T24){
      u32 id = atomicAdd(&cnt, 1u);
      if (id < 2048u) a[id] = k;
    }
  }
  __syncthreads();
  const int n = (int)min(cnt, 2048u);
  for (int k=2; k<=2048; k<<=1){
    for (int j=k>>1; j>0; j>>=1){
      for (int t=threadIdx.x; t<2048; t+=1024){
        int ix = t ^ j;
        if (ix > t){
          u64 x=a[t], y=a[ix];
          bool up = ((t & k)==0);        // descending overall
          if (up ? (x<y) : (x>y)){ a[t]=y; a[ix]=x; }
        }
      }
      __syncthreads();
    }
  }
  int KK = (int)thr[pair*4+3];
  int m = KK < n ? KK : n;
  for (int r=threadIdx.x; r<m; r+=1024) sorted[(size_t)pair*1024+r] = a[r];
  if (threadIdx.x==0) thr[pair*4+3] = (u32)m;
}

// ---------------- K6: 3-way stable merge + box decode ----------------
__global__ void merge_kernel(Ptrs p, const u32* thr, const u64* sorted,
                             float* merged, u32* mcnt){
#pragma clang fp contract(off)
  const int img = blockIdx.x;
  __shared__ u64 mk[3][1024];
  __shared__ int n[3];
  if (threadIdx.x < 3) n[threadIdx.x] = (int)thr[(img*3+threadIdx.x)*4+3];
  __syncthreads();
  const int n0=n[0], n1=n[1], n2=n[2];
  for (int idx=threadIdx.x; idx<3*1024; idx+=blockDim.x){
    int l = idx>>10, r = idx&1023;
    if (r < n[l]){
      u64 key = sorted[(size_t)(img*3+l)*1024 + r];
      mk[l][r] = (key & 0xFFFFFFFF00000000ull) |
                 (u64)(0xFFFFFFFFu - (u32)(l*PRE_K + r));  // concat-idx tie-break
    }
  }
  __syncthreads();
  const int T = n0+n1+n2;
  if (threadIdx.x==0) mcnt[img] = (u32)T;
  for (int t=threadIdx.x; t<T; t+=blockDim.x){
    int l, r;
    if (t < n0){ l=0; r=t; }
    else if (t < n0+n1){ l=1; r=t-n0; }
    else { l=2; r=t-n0-n1; }
    u64 x = mk[l][r];
    int pos = r;
    #pragma unroll
    for (int o=0;o<3;++o) if (o!=l){
      int lo=0, hi=n[o];
      while (lo<hi){ int m=(lo+hi)>>1; if (mk[o][m] > x) lo=m+1; else hi=m; }
      pos += lo;
    }
    u64 key = sorted[(size_t)(img*3+l)*1024 + r];
    u32 flat = 0xFFFFFFFFu - (u32)(key & 0xFFFFFFFFull);
    float score = __uint_as_float((u32)(key>>32));
    int HW = HWof(l);
    int loc = (int)(flat / (u32)NCLS);
    int cls = (int)(flat - (u32)loc*NCLS);
    float lx = p.locs[l][2*loc], ly = p.locs[l][2*loc+1];
    float st = STRof(l);
    const float* rg = p.reg[l] + (size_t)img*4*HW + loc;
    float r0 = rg[0]*st, r1 = rg[HW]*st, r2 = rg[2*(size_t)HW]*st, r3 = rg[3*(size_t)HW]*st;
    float x1 = fminf(fmaxf(lx - r0, 0.f), 1216.f);
    float y1 = fminf(fmaxf(ly - r1, 0.f),  800.f);
    float x2 = fminf(fmaxf(lx + r2, 0.f), 1216.f);
    float y2 = fminf(fmaxf(ly + r3, 0.f),  800.f);
    float* out = merged + (size_t)(img*3072 + pos)*8;
    out[0]=x1; out[1]=y1; out[2]=x2; out[3]=y2;
    out[4]=score; out[5]=(float)cls; out[6]=(float)l; out[7]=(float)loc;
  }
}

// ---------------- K7: greedy NMS (class-offset boxes) + output ----------------
__global__ __launch_bounds__(1024)
void nms_kernel(Ptrs p, const float* merged_all, const u32* mcnt, float* out){
#pragma clang fp contract(off)
  const int img = blockIdx.x;
  const float* merged = merged_all + (size_t)img*3072*8;
  __shared__ float4 ob[3072];
  __shared__ unsigned char keep[3072];
  __shared__ unsigned short klist[128];
  const int T = (int)mcnt[img];
  for (int j=threadIdx.x; j<3072; j+=1024){
    if (j < T){
      const float* rec = merged + (size_t)j*8;
      float off = rec[5]*1217.0f;               // replicate ref's rounded offset boxes
      ob[j] = make_float4(rec[0]+off, rec[1]+off, rec[2]+off, rec[3]+off);
      keep[j] = 1;
    } else keep[j] = 0;
  }
  __syncthreads();
  int kept = 0;
  for (int i=0; i<T; ++i){
    if (!keep[i]) continue;
    if (threadIdx.x==0) klist[kept] = (unsigned short)i;
    kept++;
    if (kept >= POST_K) break;     // later boxes can only be suppressed -> irrelevant
    float4 bi = ob[i];
    float ai = (bi.z-bi.x)*(bi.w-bi.y);
    for (int j=i+1+(int)threadIdx.x; j<T; j+=1024){
      if (!keep[j]) continue;
      float4 bj = ob[j];
      float aj = (bj.z-bj.x)*(bj.w-bj.y);
      float ltx = fmaxf(bi.x,bj.x), lty = fmaxf(bi.y,bj.y);
      float rbx = fminf(bi.z,bj.z), rby = fminf(bi.w,bj.w);
      float wx = fmaxf(rbx-ltx, 0.f), wy = fmaxf(rby-lty, 0.f);
      float inter = wx*wy;
      float denom = ai + aj;
      denom = denom - inter;
      denom = denom + 1e-9f;
      if (inter/denom > 0.6f) keep[j] = 0;
    }
    __syncthreads();
  }
  __syncthreads();
  // ---- outputs: boxes[8][100][4] | scores[8][100] | cls[8][100] | cofs[8][100][128] | kv[8][100]
  float* obx = out;
  float* osc = out + 3200;
  float* ocl = out + 4000;
  float* ocf = out + 4800;
  float* okv = out + 107200;
  for (int r=threadIdx.x; r<POST_K; r+=1024){
    if (r < kept){
      int i = klist[r];
      const float* rec = merged + (size_t)i*8;
      obx[(img*POST_K+r)*4+0]=rec[0];
      obx[(img*POST_K+r)*4+1]=rec[1];
      obx[(img*POST_K+r)*4+2]=rec[2];
      obx[(img*POST_K+r)*4+3]=rec[3];
      osc[img*POST_K+r] = sqrtf(fmaxf(rec[4], 1e-12f));
      ocl[img*POST_K+r] = rec[5];
      okv[img*POST_K+r] = 1.0f;
    } else {
      obx[(img*POST_K+r)*4+0]=0.f;
      obx[(img*POST_K+r)*4+1]=0.f;
      obx[(img*POST_K+r)*4+2]=0.f;
      obx[(img*POST_K+r)*4+3]=0.f;
      osc[img*POST_K+r] = 0.f;
      ocl[img*POST_K+r] = -1.0f;
      okv[img*POST_K+r] = 0.f;
    }
  }
  for (int q=threadIdx.x; q<POST_K*128; q+=1024){
    int r = q>>7, d = q&127;
    float v = 0.f;
    if (r < kept){
      int i = klist[r];
      const float* rec = merged + (size_t)i*8;
      int l = (int)rec[6]; int loc = (int)rec[7];
      int HW = HWof(l);
      v = p.cofs[l][((size_t)img*128 + d)*HW + loc];
    }
    ocf[(img*POST_K+r)*128 + d] = v;
  }
}

// ---------------- host ----------------
extern "C" void kernel_launch(void* const* d_in, const int* in_sizes, int n_in,
                              void* d_out, int out_size, void* d_ws, size_t ws_size,
                              hipStream_t stream){
  Ptrs p;
  for (int l=0; l<3; ++l){
    p.locs[l]   = (const float*)d_in[5*l+0];
    p.logits[l] = (const float*)d_in[5*l+1];
    p.reg[l]    = (const float*)d_in[5*l+2];
    p.ctr[l]    = (const float*)d_in[5*l+3];
    p.cofs[l]   = (const float*)d_in[5*l+4];
  }
  char* ws = (char*)d_ws;
  u32* hist1  = (u32*)(ws + OFF_HIST1);
  u32* hist2  = (u32*)(ws + OFF_HIST2);
  u32* cand   = (u32*)(ws + OFF_CAND);
  u32* acnt   = (u32*)(ws + OFF_ACNT);
  u32* bcnt   = (u32*)(ws + OFF_BCNT);
  u32* thr    = (u32*)(ws + OFF_THR);
  u32* mcnt   = (u32*)(ws + OFF_MCNT);
  float* sctr = (float*)(ws + OFF_SCTR);
  u64* apool  = (u64*)(ws + OFF_APOOL);
  u64* bpool  = (u64*)(ws + OFF_BPOOL);
  u64* sorted = (u64*)(ws + OFF_SORT);
  float* merged = (float*)(ws + OFF_MERG);

  hipMemsetAsync(ws, 0, ZERO_BYTES, stream);
  sctr_kernel<<<dim3(78,8), 256, 0, stream>>>(p, sctr);
  hist_kernel<<<dim3(240,8,3), 256, 0, stream>>>(p, sctr, hist1, cand);
  scan_kernel<false><<<24, 256, 0, stream>>>(hist1, cand, thr);
  compact_kernel<<<dim3(240,8,3), 256, 0, stream>>>(p, sctr, thr, hist2, acnt, bcnt, apool, bpool);
  scan_kernel<true><<<24, 256, 0, stream>>>(hist2, cand, thr);
  sort_kernel<<<24, 1024, 0, stream>>>(acnt, bcnt, thr, apool, bpool, sorted);
  merge_kernel<<<8, 1024, 0, stream>>>(p, thr, sorted, merged, mcnt);
  nms_kernel<<<8, 1024, 0, stream>>>(p, merged, mcnt, (float*)d_out);
}

// Round 3
// 399.706 us; speedup vs baseline: 2.7869x; 1.0234x over previous
//
#include <hip/hip_runtime.h>

typedef unsigned int u32;
typedef unsigned long long u64;

// ---------------- problem constants ----------------
#define NCLS 80
#define NIMG 8
#define PRE_K 1000
#define POST_K 100
// HW: 15200, 3800, 950 ; strides 8,16,32 ; concat bases 0,15200,19000 ; total 19950

__device__ __forceinline__ int HWof(int l){ return l==0?15200:(l==1?3800:950); }
__device__ __forceinline__ int BASEof(int l){ return l==0?0:(l==1?15200:19000); }
__device__ __forceinline__ float STRof(int l){ return l==0?8.f:(l==1?16.f:32.f); }

struct Ptrs {
  const float* logits[3];
  const float* reg[3];
  const float* ctr[3];
  const float* cofs[3];
  const float* locs[3];
};

// ---------------- workspace layout (bytes) ----------------
// zeroed every launch:
#define OFF_HIST1 0u            // 24*4096*4 = 393216
#define OFF_HIST2 393216u       // 393216
#define OFF_CAND  786432u       // 96
#define OFF_ACNT  786528u       // 96
#define OFF_BCNT  786624u       // 96
#define OFF_THR   786720u       // 24*4*4 = 384  (fields: B1, cntAbove1, T24, n_l)
#define OFF_MCNT  787104u       // 8*4
#define ZERO_BYTES 787136u
// not zeroed:
#define OFF_SCTR  787136u       // 8*19950*4 = 638400
#define OFF_APOOL 1425536u      // 24*1024*8 = 196608
#define OFF_BPOOL 1622144u      // 24*4096*8 = 786432
#define OFF_SORT  2408576u      // 24*1024*8 = 196608
#define OFF_MERG  2605184u      // 8*3072*8*4 = 786432
// total ~3391616 bytes

__device__ __forceinline__ float sigmoidf(float x){ return 1.0f/(1.0f+expf(-x)); }

// ---------------- K0: sigmoid(ctr) for all (img, concat-loc) ----------------
__global__ void sctr_kernel(Ptrs p, float* sctr){
  int img = blockIdx.y;
  int i = blockIdx.x*256 + threadIdx.x;
  if (i >= 19950) return;
  int l, loc;
  if (i < 15200){ l=0; loc=i; }
  else if (i < 19000){ l=1; loc=i-15200; }
  else { l=2; loc=i-19000; }
  int HW = HWof(l);
  float x = p.ctr[l][(size_t)img*HW + loc];
  sctr[img*19950 + i] = sigmoidf(x);
}

// ---------------- K1: coarse 4096-bin histogram (bits>>20) + cand count -----
// grid: (60*4, 8, 3); block owns 256 locs x 20 classes.
// Loads are register-batched (20 independent loads in flight) to kill the
// serial-load latency chain that round-2 counters exposed (VGPR=8, VALU 6.5%).
__global__ void hist_kernel(Ptrs p, const float* sctr, u32* hist1, u32* cand){
  const int lvl = blockIdx.z, img = blockIdx.y;
  const int HW = HWof(lvl), base = BASEof(lvl);
  const int nchunk = (HW + 255) >> 8;
  const int chunk = (int)blockIdx.x >> 2;
  const int cgrp  = (int)blockIdx.x & 3;
  if (chunk >= nchunk) return;
  const int pair = img*3 + lvl;
  __shared__ u32 lh[4096];
  __shared__ u32 lcand;
  for (int b=threadIdx.x; b<4096; b+=256) lh[b]=0;
  if (threadIdx.x==0) lcand = 0;
  __syncthreads();
  const int loc = chunk*256 + (int)threadIdx.x;
  u32 my_cand = 0;
  if (loc < HW){
    const float sc_ctr = sctr[img*19950 + base + loc];
    const float* lg = p.logits[lvl] + (size_t)(img*NCLS + cgrp*20)*HW + loc;
    float v[20];
    #pragma unroll
    for (int c=0; c<20; ++c) v[c] = lg[(size_t)c*HW];   // 20 loads in flight
    #pragma unroll
    for (int c=0; c<20; ++c){
      float sl = sigmoidf(v[c]);
      if (sl > 0.05f){
        my_cand++;
        u32 bits = __float_as_uint(sl * sc_ctr);
        atomicAdd(&lh[bits>>20], 1u);
      }
    }
  }
  if (my_cand) atomicAdd(&lcand, my_cand);
  __syncthreads();
  if (threadIdx.x==0 && lcand) atomicAdd(&cand[pair], lcand);
  for (int b=threadIdx.x; b<4096; b+=256){
    u32 v = lh[b];
    if (v) atomicAdd(&hist1[pair*4096+b], v);
  }
}

// ---------------- K2/K4: descending scan to find boundary bin ----------------
template<bool FINE>
__global__ void scan_kernel(const u32* hist, const u32* cand, u32* thr){
  const int pair = blockIdx.x;
  const u32* h = hist + pair*4096;
  __shared__ u32 seg[256];
  __shared__ u32 excl[256];
  __shared__ u32 sKK;
  if (threadIdx.x==0){
    u32 kk = cand[pair]; if (kk > (u32)PRE_K) kk = PRE_K;
    if (FINE){
      if (kk) kk -= thr[pair*4+1];
    } else {
      thr[pair*4+3] = kk;               // n_l (provisional)
      if (kk==0){ thr[pair*4+0]=0xFFFFu; thr[pair*4+2]=0xFFFFFFFFu; }
    }
    sKK = kk;
  }
  __syncthreads();
  u32 KK = sKK;
  if (KK==0) return;
  int t = threadIdx.x;
  u32 part = 0;
  for (int k=0;k<16;++k) part += h[4095 - (t*16+k)];
  seg[t] = part;
  __syncthreads();
  if (t==0){ u32 run=0; for (int i=0;i<256;++i){ excl[i]=run; run+=seg[i]; } }
  __syncthreads();
  u32 cum = excl[t];
  for (int k=0;k<16;++k){
    int bin = 4095 - (t*16+k);
    u32 c = h[bin];
    if (c && cum < KK && cum + c >= KK){
      if (!FINE){ thr[pair*4+0]=(u32)bin; thr[pair*4+1]=cum; }
      else {
        u32 B1 = thr[pair*4+0];
        thr[pair*4+2] = (B1<<12) | (u32)bin;   // T24 threshold on bits>>8
      }
    }
    cum += c;
  }
}

// ---------------- K3: fused compact + refine (single extra data pass) --------
// coarse bin > B1 -> apool (guaranteed < 1000 per pair)
// coarse bin == B1 -> bpool + direct global fine-hist atomic
__global__ void compact_kernel(Ptrs p, const float* sctr, const u32* thr,
                               u32* hist2, u32* acnt, u32* bcnt,
                               u64* apool, u64* bpool){
  const int lvl = blockIdx.z, img = blockIdx.y;
  const int HW = HWof(lvl), base = BASEof(lvl);
  const int nchunk = (HW + 255) >> 8;
  const int chunk = (int)blockIdx.x >> 2;
  const int cgrp  = (int)blockIdx.x & 3;
  if (chunk >= nchunk) return;
  const int pair = img*3 + lvl;
  const u32 B1 = thr[pair*4+0];
  const int loc = chunk*256 + (int)threadIdx.x;
  if (loc >= HW) return;
  const float sc_ctr = sctr[img*19950 + base + loc];
  const float* lg = p.logits[lvl] + (size_t)(img*NCLS + cgrp*20)*HW + loc;
  float v[20];
  #pragma unroll
  for (int c=0; c<20; ++c) v[c] = lg[(size_t)c*HW];     // 20 loads in flight
  #pragma unroll
  for (int c=0; c<20; ++c){
    float sl = sigmoidf(v[c]);
    if (sl > 0.05f){
      u32 bits = __float_as_uint(sl * sc_ctr);
      u32 b1 = bits>>20;
      if (b1 > B1){
        u32 i = atomicAdd(&acnt[pair], 1u);
        if (i < 1024u)
          apool[(size_t)pair*1024 + i] =
            ((u64)bits<<32) | (u64)(0xFFFFFFFFu - (u32)(loc*NCLS + cgrp*20 + c));
      } else if (b1 == B1){
        atomicAdd(&hist2[pair*4096 + ((bits>>8)&0xFFFu)], 1u);
        u32 i = atomicAdd(&bcnt[pair], 1u);
        if (i < 4096u)
          bpool[(size_t)pair*4096 + i] =
            ((u64)bits<<32) | (u64)(0xFFFFFFFFu - (u32)(loc*NCLS + cgrp*20 + c));
      }
    }
  }
}

// ---------------- K5: gather apool + filtered bpool, bitonic sort, top n_l ---
__global__ __launch_bounds__(1024)
void sort_kernel(const u32* acnt, const u32* bcnt, u32* thr,
                 const u64* apool, const u64* bpool, u64* sorted){
  const int pair = blockIdx.x;
  __shared__ u64 a[2048];
  __shared__ u32 cnt;
  const int na = (int)min(acnt[pair], 1024u);
  for (int i=threadIdx.x; i<2048; i+=1024) a[i] = 0ull;
  if (threadIdx.x==0) cnt = (u32)na;
  __syncthreads();
  for (int i=threadIdx.x; i<na; i+=1024) a[i] = apool[(size_t)pair*1024 + i];
  const u32 T24 = thr[pair*4+2];
  const int nb = (int)min(bcnt[pair], 4096u);
  for (int i=threadIdx.x; i<nb; i+=1024){
    u64 k = bpool[(size_t)pair*4096 + i];
    if ((u32)(k>>40) >= T24){
      u32 id = atomicAdd(&cnt, 1u);
      if (id < 2048u) a[id] = k;
    }
  }
  __syncthreads();
  const int n = (int)min(cnt, 2048u);
  for (int k=2; k<=2048; k<<=1){
    for (int j=k>>1; j>0; j>>=1){
      for (int t=threadIdx.x; t<2048; t+=1024){
        int ix = t ^ j;
        if (ix > t){
          u64 x=a[t], y=a[ix];
          bool up = ((t & k)==0);        // descending overall
          if (up ? (x<y) : (x>y)){ a[t]=y; a[ix]=x; }
        }
      }
      __syncthreads();
    }
  }
  int KK = (int)thr[pair*4+3];
  int m = KK < n ? KK : n;
  for (int r=threadIdx.x; r<m; r+=1024) sorted[(size_t)pair*1024+r] = a[r];
  if (threadIdx.x==0) thr[pair*4+3] = (u32)m;
}

// ---------------- K6: 3-way stable merge + box decode ----------------
__global__ void merge_kernel(Ptrs p, const u32* thr, const u64* sorted,
                             float* merged, u32* mcnt){
#pragma clang fp contract(off)
  const int img = blockIdx.x;
  __shared__ u64 mk[3][1024];
  __shared__ int n[3];
  if (threadIdx.x < 3) n[threadIdx.x] = (int)thr[(img*3+threadIdx.x)*4+3];
  __syncthreads();
  const int n0=n[0], n1=n[1], n2=n[2];
  for (int idx=threadIdx.x; idx<3*1024; idx+=blockDim.x){
    int l = idx>>10, r = idx&1023;
    if (r < n[l]){
      u64 key = sorted[(size_t)(img*3+l)*1024 + r];
      mk[l][r] = (key & 0xFFFFFFFF00000000ull) |
                 (u64)(0xFFFFFFFFu - (u32)(l*PRE_K + r));  // concat-idx tie-break
    }
  }
  __syncthreads();
  const int T = n0+n1+n2;
  if (threadIdx.x==0) mcnt[img] = (u32)T;
  for (int t=threadIdx.x; t<T; t+=blockDim.x){
    int l, r;
    if (t < n0){ l=0; r=t; }
    else if (t < n0+n1){ l=1; r=t-n0; }
    else { l=2; r=t-n0-n1; }
    u64 x = mk[l][r];
    int pos = r;
    #pragma unroll
    for (int o=0;o<3;++o) if (o!=l){
      int lo=0, hi=n[o];
      while (lo<hi){ int m=(lo+hi)>>1; if (mk[o][m] > x) lo=m+1; else hi=m; }
      pos += lo;
    }
    u64 key = sorted[(size_t)(img*3+l)*1024 + r];
    u32 flat = 0xFFFFFFFFu - (u32)(key & 0xFFFFFFFFull);
    float score = __uint_as_float((u32)(key>>32));
    int HW = HWof(l);
    int loc = (int)(flat / (u32)NCLS);
    int cls = (int)(flat - (u32)loc*NCLS);
    float lx = p.locs[l][2*loc], ly = p.locs[l][2*loc+1];
    float st = STRof(l);
    const float* rg = p.reg[l] + (size_t)img*4*HW + loc;
    float r0 = rg[0]*st, r1 = rg[HW]*st, r2 = rg[2*(size_t)HW]*st, r3 = rg[3*(size_t)HW]*st;
    float x1 = fminf(fmaxf(lx - r0, 0.f), 1216.f);
    float y1 = fminf(fmaxf(ly - r1, 0.f),  800.f);
    float x2 = fminf(fmaxf(lx + r2, 0.f), 1216.f);
    float y2 = fminf(fmaxf(ly + r3, 0.f),  800.f);
    float* out = merged + (size_t)(img*3072 + pos)*8;
    out[0]=x1; out[1]=y1; out[2]=x2; out[3]=y2;
    out[4]=score; out[5]=(float)cls; out[6]=(float)l; out[7]=(float)loc;
  }
}

// ---------------- K7: greedy NMS (class-offset boxes) + output ----------------
__global__ __launch_bounds__(1024)
void nms_kernel(Ptrs p, const float* merged_all, const u32* mcnt, float* out){
#pragma clang fp contract(off)
  const int img = blockIdx.x;
  const float* merged = merged_all + (size_t)img*3072*8;
  __shared__ float4 ob[3072];
  __shared__ unsigned char keep[3072];
  __shared__ unsigned short klist[128];
  const int T = (int)mcnt[img];
  for (int j=threadIdx.x; j<3072; j+=1024){
    if (j < T){
      const float* rec = merged + (size_t)j*8;
      float off = rec[5]*1217.0f;               // replicate ref's rounded offset boxes
      ob[j] = make_float4(rec[0]+off, rec[1]+off, rec[2]+off, rec[3]+off);
      keep[j] = 1;
    } else keep[j] = 0;
  }
  __syncthreads();
  int kept = 0;
  for (int i=0; i<T; ++i){
    if (!keep[i]) continue;
    if (threadIdx.x==0) klist[kept] = (unsigned short)i;
    kept++;
    if (kept >= POST_K) break;     // later boxes can only be suppressed -> irrelevant
    float4 bi = ob[i];
    float ai = (bi.z-bi.x)*(bi.w-bi.y);
    for (int j=i+1+(int)threadIdx.x; j<T; j+=1024){
      if (!keep[j]) continue;
      float4 bj = ob[j];
      float aj = (bj.z-bj.x)*(bj.w-bj.y);
      float ltx = fmaxf(bi.x,bj.x), lty = fmaxf(bi.y,bj.y);
      float rbx = fminf(bi.z,bj.z), rby = fminf(bi.w,bj.w);
      float wx = fmaxf(rbx-ltx, 0.f), wy = fmaxf(rby-lty, 0.f);
      float inter = wx*wy;
      float denom = ai + aj;
      denom = denom - inter;
      denom = denom + 1e-9f;
      if (inter/denom > 0.6f) keep[j] = 0;
    }
    __syncthreads();
  }
  __syncthreads();
  // ---- outputs: boxes[8][100][4] | scores[8][100] | cls[8][100] | cofs[8][100][128] | kv[8][100]
  float* obx = out;
  float* osc = out + 3200;
  float* ocl = out + 4000;
  float* ocf = out + 4800;
  float* okv = out + 107200;
  for (int r=threadIdx.x; r<POST_K; r+=1024){
    if (r < kept){
      int i = klist[r];
      const float* rec = merged + (size_t)i*8;
      obx[(img*POST_K+r)*4+0]=rec[0];
      obx[(img*POST_K+r)*4+1]=rec[1];
      obx[(img*POST_K+r)*4+2]=rec[2];
      obx[(img*POST_K+r)*4+3]=rec[3];
      osc[img*POST_K+r] = sqrtf(fmaxf(rec[4], 1e-12f));
      ocl[img*POST_K+r] = rec[5];
      okv[img*POST_K+r] = 1.0f;
    } else {
      obx[(img*POST_K+r)*4+0]=0.f;
      obx[(img*POST_K+r)*4+1]=0.f;
      obx[(img*POST_K+r)*4+2]=0.f;
      obx[(img*POST_K+r)*4+3]=0.f;
      osc[img*POST_K+r] = 0.f;
      ocl[img*POST_K+r] = -1.0f;
      okv[img*POST_K+r] = 0.f;
    }
  }
  for (int q=threadIdx.x; q<POST_K*128; q+=1024){
    int r = q>>7, d = q&127;
    float v = 0.f;
    if (r < kept){
      int i = klist[r];
      const float* rec = merged + (size_t)i*8;
      int l = (int)rec[6]; int loc = (int)rec[7];
      int HW = HWof(l);
      v = p.cofs[l][((size_t)img*128 + d)*HW + loc];
    }
    ocf[(img*POST_K+r)*128 + d] = v;
  }
}

// ---------------- host ----------------
extern "C" void kernel_launch(void* const* d_in, const int* in_sizes, int n_in,
                              void* d_out, int out_size, void* d_ws, size_t ws_size,
                              hipStream_t stream){
  Ptrs p;
  for (int l=0; l<3; ++l){
    p.locs[l]   = (const float*)d_in[5*l+0];
    p.logits[l] = (const float*)d_in[5*l+1];
    p.reg[l]    = (const float*)d_in[5*l+2];
    p.ctr[l]    = (const float*)d_in[5*l+3];
    p.cofs[l]   = (const float*)d_in[5*l+4];
  }
  char* ws = (char*)d_ws;
  u32* hist1  = (u32*)(ws + OFF_HIST1);
  u32* hist2  = (u32*)(ws + OFF_HIST2);
  u32* cand   = (u32*)(ws + OFF_CAND);
  u32* acnt   = (u32*)(ws + OFF_ACNT);
  u32* bcnt   = (u32*)(ws + OFF_BCNT);
  u32* thr    = (u32*)(ws + OFF_THR);
  u32* mcnt   = (u32*)(ws + OFF_MCNT);
  float* sctr = (float*)(ws + OFF_SCTR);
  u64* apool  = (u64*)(ws + OFF_APOOL);
  u64* bpool  = (u64*)(ws + OFF_BPOOL);
  u64* sorted = (u64*)(ws + OFF_SORT);
  float* merged = (float*)(ws + OFF_MERG);

  hipMemsetAsync(ws, 0, ZERO_BYTES, stream);
  sctr_kernel<<<dim3(78,8), 256, 0, stream>>>(p, sctr);
  hist_kernel<<<dim3(240,8,3), 256, 0, stream>>>(p, sctr, hist1, cand);
  scan_kernel<false><<<24, 256, 0, stream>>>(hist1, cand, thr);
  compact_kernel<<<dim3(240,8,3), 256, 0, stream>>>(p, sctr, thr, hist2, acnt, bcnt, apool, bpool);
  scan_kernel<true><<<24, 256, 0, stream>>>(hist2, cand, thr);
  sort_kernel<<<24, 1024, 0, stream>>>(acnt, bcnt, thr, apool, bpool, sorted);
  merge_kernel<<<8, 1024, 0, stream>>>(p, thr, sorted, merged, mcnt);
  nms_kernel<<<8, 1024, 0, stream>>>(p, merged, mcnt, (float*)d_out);
}